// Round 2
// baseline (330.943 us; speedup 1.0000x reference)
//
#include <hip/hip_runtime.h>
#include <math.h>

#define B_ 2
#define L_ 1024
#define D_ 512
#define NROW (B_*L_)            // 2048
#define RS 896                  // R stride: key16|query16|g1 256|v 512|pad 96
#define PI_F 3.14159274f
#define TWO_PI_F 6.28318548f
#define NBLK 256

typedef __attribute__((ext_vector_type(8))) short bf16x8;
typedef __attribute__((ext_vector_type(4))) float f32x4;

__device__ __forceinline__ unsigned short f2bf(float f) {
    unsigned u = __float_as_uint(f);
    unsigned r = (u + 0x7FFFu + ((u >> 16) & 1u)) >> 16;
    return (unsigned short)r;
}

// device-scope grid barrier: one counter per barrier, zeroed host-side.
// release: syncthreads (drains each wave's stores) + threadfence (wbL2);
// acquire: spin on agent-scope load + threadfence (invL1/L2).
__device__ __forceinline__ void gridbar(unsigned* c, unsigned nb) {
    __syncthreads();
    if (threadIdx.x == 0) {
        __threadfence();
        atomicAdd(c, 1u);
        while (__hip_atomic_load(c, __ATOMIC_RELAXED, __HIP_MEMORY_SCOPE_AGENT) < nb)
            __builtin_amdgcn_s_sleep(2);
        __threadfence();
    }
    __syncthreads();
}

template<int CCH, int CLEN>
__global__ __launch_bounds__(256, 2) void k_fused(
    unsigned* __restrict__ bar,
    const float* __restrict__ x,
    const float* __restrict__ keyw, const float* __restrict__ qryw,
    const float* __restrict__ g1w, const float* __restrict__ vw,
    const float* __restrict__ outw,
    const float* __restrict__ g1b, const float* __restrict__ vb,
    const float* __restrict__ pf, const float* __restrict__ g2w,
    const float* __restrict__ g2b,
    const float* __restrict__ rscale, const float* __restrict__ rthr,
    const float* __restrict__ sscale, const float* __restrict__ sbias,
    const float* __restrict__ setw, const float* __restrict__ posw,
    const float* __restrict__ lng, const float* __restrict__ lnb,
    const float* __restrict__ outb,
    float* R, float* scal, float* loc, float* T,
    unsigned short* W, unsigned short* locb,
    float* out)
{
    __shared__ __align__(16) char smem[12288];
    const int bx = blockIdx.x;
    const int tid = threadIdx.x;

    // ================= phase 0: weight prep (176 works) =================
    if (bx < 176) {
        unsigned short* tile = (unsigned short*)smem;   // [64][68]
        const int nt = bx % 22;
        const int kt = bx / 22;
        const int n0 = nt * 64, k0 = kt * 64;
        const int tn = tid & 63;
        const int tk4 = tid >> 6;
        const int n = n0 + tn;
        const float* src = nullptr; int stride = 0, col = 0;
        if (n < 16)        { src = keyw; stride = 16;  col = n; }
        else if (n < 32)   { src = qryw; stride = 16;  col = n - 16; }
        else if (n < 288)  { src = g1w;  stride = 256; col = n - 32; }
        else if (n < 800)  { src = vw;   stride = 512; col = n - 288; }
        else if (n < 896)  { src = nullptr; }
        else               { src = outw; stride = 512; col = n - 896; }
        #pragma unroll
        for (int r = 0; r < 16; ++r) {
            int k = k0 + tk4 * 16 + r;
            float v = src ? src[(size_t)k * stride + col] : 0.f;
            tile[(tk4 * 16 + r) * 68 + tn] = f2bf(v);
        }
        __syncthreads();
        #pragma unroll
        for (int r = 0; r < 16; ++r) {
            int nn = n0 + tk4 * 16 + r;
            W[(size_t)nn * 512 + k0 + tn] = tile[tn * 68 + tk4 * 16 + r];
        }
    }
    gridbar(bar + 0, NBLK);

    // ================= phase 1: GEMM1 (224 works) =================
    if (bx < 224) {
        unsigned short* As = (unsigned short*)smem;        // 64*32
        unsigned short* Bs = As + 64 * 32;                 // 128*32
        const int w = tid >> 6;
        const int lane = tid & 63;
        const int m0 = (bx / 7) * 64;
        const int n0 = (bx % 7) * 128;
        const int srow = tid >> 2;
        const int scol = (tid & 3) * 8;
        f32x4 acc[4][2];
        #pragma unroll
        for (int mt = 0; mt < 4; ++mt)
            #pragma unroll
            for (int nt2 = 0; nt2 < 2; ++nt2)
                acc[mt][nt2] = (f32x4){0.f, 0.f, 0.f, 0.f};
        const float* ap = x + (size_t)(m0 + srow) * 512 + scol;
        const unsigned short* bp0 = W + (size_t)(n0 + srow) * 512 + scol;
        const unsigned short* bp1 = W + (size_t)(n0 + 64 + srow) * 512 + scol;
        const int quad = lane >> 4, r16 = lane & 15;
        for (int k0 = 0; k0 < 512; k0 += 32) {
            float4 a0 = *(const float4*)(ap + k0);
            float4 a1 = *(const float4*)(ap + k0 + 4);
            int4 bv0 = *(const int4*)(bp0 + k0);
            int4 bv1 = *(const int4*)(bp1 + k0);
            int4 av;
            av.x = (int)f2bf(a0.x) | ((int)f2bf(a0.y) << 16);
            av.y = (int)f2bf(a0.z) | ((int)f2bf(a0.w) << 16);
            av.z = (int)f2bf(a1.x) | ((int)f2bf(a1.y) << 16);
            av.w = (int)f2bf(a1.z) | ((int)f2bf(a1.w) << 16);
            __syncthreads();
            *(int4*)&As[srow * 32 + scol] = av;
            *(int4*)&Bs[srow * 32 + scol] = bv0;
            *(int4*)&Bs[(64 + srow) * 32 + scol] = bv1;
            __syncthreads();
            bf16x8 af[4], bfr[2];
            #pragma unroll
            for (int mt = 0; mt < 4; ++mt)
                af[mt] = *(const bf16x8*)&As[(mt * 16 + r16) * 32 + quad * 8];
            #pragma unroll
            for (int nt2 = 0; nt2 < 2; ++nt2)
                bfr[nt2] = *(const bf16x8*)&Bs[(w * 32 + nt2 * 16 + r16) * 32 + quad * 8];
            #pragma unroll
            for (int mt = 0; mt < 4; ++mt)
                #pragma unroll
                for (int nt2 = 0; nt2 < 2; ++nt2)
                    acc[mt][nt2] = __builtin_amdgcn_mfma_f32_16x16x32_bf16(
                        af[mt], bfr[nt2], acc[mt][nt2], 0, 0, 0);
        }
        #pragma unroll
        for (int mt = 0; mt < 4; ++mt) {
            #pragma unroll
            for (int nt2 = 0; nt2 < 2; ++nt2) {
                const int n = n0 + w * 32 + nt2 * 16 + r16;
                float bias = 0.f;
                if (n >= 288 && n < 800) bias = vb[n - 288];
                else if (n >= 32 && n < 288) bias = g1b[n - 32];
                #pragma unroll
                for (int i = 0; i < 4; ++i) {
                    const int m = m0 + mt * 16 + quad * 4 + i;
                    R[(size_t)m * RS + n] = acc[mt][nt2][i] + bias;
                }
            }
        }
    }
    gridbar(bar + 1, NBLK);

    // ================= phase 2: phasor (512 works, 2 per block) =================
    {
        #pragma unroll
        for (int rep = 0; rep < 2; ++rep) {
            const int row = (bx * 2 + rep) * 4 + (tid >> 6);
            const int lane = tid & 63;
            const int l = row & (L_ - 1);
            float* sc = scal + (size_t)row * 128;
            const float* r = R + (size_t)row * RS;
            float part = 0.f;
            #pragma unroll
            for (int j = 0; j < 4; ++j) {
                float v = r[32 + lane * 4 + j];
                float h = 0.5f * v * (1.0f + erff(v * 0.70710678f));
                part += h * g2w[lane * 4 + j];
            }
            #pragma unroll
            for (int off = 32; off > 0; off >>= 1) part += __shfl_down(part, off, 64);
            if (lane == 0) sc[112] = 1.0f / (1.0f + expf(-(part + g2b[0])));
            float pr = 1.f, pim = 0.f;
            if (lane < 32) {
                float a = tanhf(r[lane]) * PI_F;
                float sv, cv;
                sincosf(a, &sv, &cv);
                int t = lane & 15;
                if (lane < 16) { sc[t] = cv; sc[16 + t] = sv; }
                else           { sc[32 + t] = cv; sc[48 + t] = sv; }
                pr = cv; pim = sv;
            }
            #pragma unroll
            for (int m = 4; m <= 8; m <<= 1) {
                float orr = __shfl_xor(pr, m, 64);
                float oii = __shfl_xor(pim, m, 64);
                float nr = pr * orr - pim * oii;
                float ni = pr * oii + pim * orr;
                pr = nr; pim = ni;
            }
            if (lane < 4)                     { sc[64 + lane] = pr; sc[68 + lane] = pim; }
            else if (lane >= 16 && lane < 20) { sc[72 + lane - 16] = pr; sc[76 + lane - 16] = pim; }
            if (lane >= 32 && lane < 48) {
                int p = lane - 32;
                float theta = ((float)l * pf[p]) * TWO_PI_F;
                float sv, cv;
                sincosf(theta, &sv, &cv);
                sc[80 + p] = cv;
                sc[96 + p] = sv;
            }
        }
    }
    gridbar(bar + 2, NBLK);

    // ================= phase 3: wg scan (blocks 0..1) =================
    if (bx < B_) {
        const int b = bx;
        const int lane = tid & 63, wv = tid >> 6;   // 4 waves
        float* wt = (float*)smem;                    // [4][8]
        float rowv[4][8];
        float cum[8];
        #pragma unroll
        for (int c2 = 0; c2 < 8; ++c2) cum[c2] = 0.f;
        #pragma unroll
        for (int j = 0; j < 4; ++j) {
            const size_t row = (size_t)(b * L_ + tid * 4 + j) * 128;
            #pragma unroll
            for (int c2 = 0; c2 < 8; ++c2) {
                float v = scal[row + 64 + c2];
                rowv[j][c2] = v; cum[c2] += v;
            }
        }
        float inc[8];
        #pragma unroll
        for (int c2 = 0; c2 < 8; ++c2) inc[c2] = cum[c2];
        #pragma unroll
        for (int off = 1; off < 64; off <<= 1) {
            float o[8];
            #pragma unroll
            for (int c2 = 0; c2 < 8; ++c2) o[c2] = __shfl_up(inc[c2], off, 64);
            if (lane >= off) {
                #pragma unroll
                for (int c2 = 0; c2 < 8; ++c2) inc[c2] += o[c2];
            }
        }
        if (lane == 63) {
            #pragma unroll
            for (int c2 = 0; c2 < 8; ++c2) wt[wv * 8 + c2] = inc[c2];
        }
        __syncthreads();
        float run[8];
        #pragma unroll
        for (int c2 = 0; c2 < 8; ++c2) run[c2] = inc[c2] - cum[c2];
        for (int w2 = 0; w2 < wv; ++w2) {
            #pragma unroll
            for (int c2 = 0; c2 < 8; ++c2) run[c2] += wt[w2 * 8 + c2];
        }
        const float scl = fminf(fmaxf(rscale[0], 1.0f), 20.0f);
        const float thr = fminf(fmaxf(rthr[0], 0.1f), 0.9f);
        const float ss = sscale[0], sb = sbias[0];
        #pragma unroll
        for (int j = 0; j < 4; ++j) {
            const int l = tid * 4 + j;
            const size_t row = (size_t)(b * L_ + l) * 128;
            float mag = 0.f;
            #pragma unroll
            for (int pp = 0; pp < 4; ++pp) {
                float jqr = scal[row + 72 + pp], jqi = scal[row + 76 + pp];
                float re = run[pp] * jqr + run[4 + pp] * jqi;
                float im = run[4 + pp] * jqr - run[pp] * jqi;
                mag += sqrtf(re * re + im * im);
            }
            mag *= 0.25f;
            float posn = fmaxf((float)l, 1.0f);
            float nres = mag / sqrtf(posn);
            float sur = 0.5f * (1.0f - tanhf(scl * (nres - thr)));
            scal[row + 113] = 1.0f / (1.0f + expf(-(ss * (sur - 0.5f) + sb)));
            #pragma unroll
            for (int c2 = 0; c2 < 8; ++c2) run[c2] += rowv[j][c2];
        }
    }
    gridbar(bar + 3, NBLK);

    // ================= phase 4: passA (B_*CCH*2 works) =================
    if (bx < B_ * CCH * 2) {
        const int b = bx / (CCH * 2);
        const int rem = bx % (CCH * 2);
        const int c = rem >> 1;
        const int half = rem & 1;
        const int d = half * 256 + tid;
        float s0 = setw[0], s1 = setw[1], s2 = setw[2], s3 = setw[3];
        float mx = fmaxf(fmaxf(s0, s1), fmaxf(s2, s3));
        float e0 = expf(s0 - mx), e1 = expf(s1 - mx), e2 = expf(s2 - mx), e3 = expf(s3 - mx);
        float esum = e0 + e1 + e2 + e3;
        float w[4] = {e0 / esum, e1 / esum, e2 / esum, e3 / esum};
        float sw = 1.0f / (1.0f + expf(-posw[0]));
        float Sr[16] = {}, Si[16] = {}, Xr[4] = {}, Xi[4] = {}, Pr[16] = {}, Pi[16] = {};
        for (int i = 0; i < CLEN; ++i) {
            const int l = c * CLEN + i;
            const size_t row = (size_t)(b * L_ + l);
            const float4* sc4 = (const float4*)(scal + row * 128);
            float V = R[row * RS + 288 + d];
            float4 gw = sc4[28];
            float gate = gw.x, wg = gw.y;
            float Vg = V * wg;
            float pb = 0.f, cross = 0.f, pos = 0.f;
            #pragma unroll
            for (int g4 = 0; g4 < 4; ++g4) {
                float kr[4], ki[4], qr[4], qi[4];
                *(float4*)kr = sc4[g4];      *(float4*)ki = sc4[4 + g4];
                *(float4*)qr = sc4[8 + g4];  *(float4*)qi = sc4[12 + g4];
                #pragma unroll
                for (int j = 0; j < 4; ++j) {
                    int t = 4 * g4 + j;
                    Sr[t] += kr[j] * Vg; Si[t] += ki[j] * Vg;
                    pb += w[g4] * (Sr[t] * qr[j] + Si[t] * qi[j]);
                }
            }
            {
                float jkr[4], jki[4], jqr[4], jqi[4];
                *(float4*)jkr = sc4[16]; *(float4*)jki = sc4[17];
                *(float4*)jqr = sc4[18]; *(float4*)jqi = sc4[19];
                #pragma unroll
                for (int pp = 0; pp < 4; ++pp) {
                    Xr[pp] += jkr[pp] * Vg; Xi[pp] += jki[pp] * Vg;
                    cross += Xr[pp] * jqr[pp] + Xi[pp] * jqi[pp];
                }
            }
            #pragma unroll
            for (int g4 = 0; g4 < 4; ++g4) {
                float phr[4], phi[4];
                *(float4*)phr = sc4[20 + g4]; *(float4*)phi = sc4[24 + g4];
                #pragma unroll
                for (int j = 0; j < 4; ++j) {
                    int p = 4 * g4 + j;
                    Pr[p] += phr[j] * V; Pi[p] += phi[j] * V;
                    pos += Pr[p] * phr[j] + Pi[p] * phi[j];
                }
            }
            float comb = gate * ((pb + cross) * 0.2f) + (1.0f - gate) * (sw * pos);
            loc[row * D_ + d] = comb;
        }
        const size_t tb = ((size_t)(b * CCH + c) * 72) * D_ + d;
        #pragma unroll
        for (int t = 0; t < 16; ++t) { T[tb + (size_t)(2*t)*D_] = Sr[t]; T[tb + (size_t)(2*t+1)*D_] = Si[t]; }
        #pragma unroll
        for (int pp = 0; pp < 4; ++pp) { T[tb + (size_t)(32+2*pp)*D_] = Xr[pp]; T[tb + (size_t)(33+2*pp)*D_] = Xi[pp]; }
        #pragma unroll
        for (int p = 0; p < 16; ++p) { T[tb + (size_t)(40+2*p)*D_] = Pr[p]; T[tb + (size_t)(41+2*p)*D_] = Pi[p]; }
    }
    gridbar(bar + 4, NBLK);

    // ================= phase 5: chunk-total exclusive scan =================
    {
        const size_t cstride = (size_t)72 * D_;
        for (int idx = bx * 256 + tid; idx < B_ * 72 * D_; idx += NBLK * 256) {
            const int d = idx & 511;
            const int ch = (idx >> 9) % 72;
            const int b = idx / (512 * 72);
            const size_t base = ((size_t)b * CCH * 72 + ch) * D_ + d;
            float run = 0.f;
            for (int c0 = 0; c0 < CCH; c0 += 8) {
                float v[8];
                #pragma unroll
                for (int j = 0; j < 8; ++j) v[j] = T[base + (size_t)(c0 + j) * cstride];
                #pragma unroll
                for (int j = 0; j < 8; ++j) {
                    T[base + (size_t)(c0 + j) * cstride] = run;
                    run += v[j];
                }
            }
        }
    }
    gridbar(bar + 5, NBLK);

    // ================= phase 6: passB (256 works, 2 d-halves/block) =================
    {
        const int SUBS = CLEN / 8;
        const int b = bx / (CCH * SUBS);
        const int rem = bx % (CCH * SUBS);
        const int c = rem / SUBS;
        const int sub = rem % SUBS;
        const int lane = tid & 63, wv = tid >> 6;     // 4 waves
        float* red = (float*)smem;                     // [2][8][4][2] = 128 floats
        float s0 = setw[0], s1 = setw[1], s2 = setw[2], s3 = setw[3];
        float mx = fmaxf(fmaxf(s0, s1), fmaxf(s2, s3));
        float e0 = expf(s0 - mx), e1 = expf(s1 - mx), e2 = expf(s2 - mx), e3 = expf(s3 - mx);
        float esum = e0 + e1 + e2 + e3;
        float w[4] = {e0 / esum, e1 / esum, e2 / esum, e3 / esum};
        float sw = 1.0f / (1.0f + expf(-posw[0]));
        float y[2][8];
        #pragma unroll
        for (int h = 0; h < 2; ++h) {
            const int d = h * 256 + tid;
            float Pf[72];
            const size_t tb = ((size_t)(b * CCH + c) * 72) * D_ + d;
            #pragma unroll
            for (int ch = 0; ch < 72; ++ch) Pf[ch] = T[tb + (size_t)ch * D_];
            #pragma unroll
            for (int i = 0; i < 8; ++i) {
                const int l = c * CLEN + sub * 8 + i;
                const size_t row = (size_t)(b * L_ + l);
                const float4* sc4 = (const float4*)(scal + row * 128);
                float gate = sc4[28].x;
                float pb = 0.f, cross = 0.f, pos = 0.f;
                #pragma unroll
                for (int g4 = 0; g4 < 4; ++g4) {
                    float qr[4], qi[4];
                    *(float4*)qr = sc4[8 + g4]; *(float4*)qi = sc4[12 + g4];
                    #pragma unroll
                    for (int j = 0; j < 4; ++j) {
                        int t = 4 * g4 + j;
                        pb += w[g4] * (Pf[2*t] * qr[j] + Pf[2*t+1] * qi[j]);
                    }
                }
                {
                    float jqr[4], jqi[4];
                    *(float4*)jqr = sc4[18]; *(float4*)jqi = sc4[19];
                    #pragma unroll
                    for (int pp = 0; pp < 4; ++pp)
                        cross += Pf[32+2*pp] * jqr[pp] + Pf[33+2*pp] * jqi[pp];
                }
                #pragma unroll
                for (int g4 = 0; g4 < 4; ++g4) {
                    float phr[4], phi[4];
                    *(float4*)phr = sc4[20 + g4]; *(float4*)phi = sc4[24 + g4];
                    #pragma unroll
                    for (int j = 0; j < 4; ++j) {
                        int p = 4 * g4 + j;
                        pos += Pf[40+2*p] * phr[j] + Pf[41+2*p] * phi[j];
                    }
                }
                float addl = gate * ((pb + cross) * 0.2f) + (1.0f - gate) * (sw * pos);
                float yv = (loc[row * D_ + d] + addl) / sqrtf(4.0f * (float)(l + 1));
                y[h][i] = yv;
                float s = yv, s2v = yv * yv;
                #pragma unroll
                for (int off = 32; off > 0; off >>= 1) {
                    s   += __shfl_down(s, off, 64);
                    s2v += __shfl_down(s2v, off, 64);
                }
                if (lane == 0) {
                    red[((h * 8 + i) * 4 + wv) * 2]     = s;
                    red[((h * 8 + i) * 4 + wv) * 2 + 1] = s2v;
                }
            }
        }
        __syncthreads();
        const float lg0 = lng[tid],       lb0 = lnb[tid];
        const float lg1 = lng[256 + tid], lb1 = lnb[256 + tid];
        #pragma unroll
        for (int i = 0; i < 8; ++i) {
            float su = 0.f, sq = 0.f;
            #pragma unroll
            for (int h2 = 0; h2 < 2; ++h2)
                #pragma unroll
                for (int w2 = 0; w2 < 4; ++w2) {
                    su += red[((h2 * 8 + i) * 4 + w2) * 2];
                    sq += red[((h2 * 8 + i) * 4 + w2) * 2 + 1];
                }
            float mu = su * (1.0f / 512.0f);
            float var = sq * (1.0f / 512.0f) - mu * mu;
            float rstd = rsqrtf(var + 1e-5f);
            const int l = c * CLEN + sub * 8 + i;
            const size_t row = (size_t)(b * L_ + l);
            locb[row * D_ + tid]       = f2bf((y[0][i] - mu) * rstd * lg0 + lb0);
            locb[row * D_ + 256 + tid] = f2bf((y[1][i] - mu) * rstd * lg1 + lb1);
        }
    }
    gridbar(bar + 6, NBLK);

    // ================= phase 7: out GEMM (256 works) =================
    {
        unsigned short* As = (unsigned short*)smem;
        unsigned short* Bs = As + 64 * 32;
        const unsigned short* OWt = W + (size_t)896 * 512;
        const int w = tid >> 6;
        const int lane = tid & 63;
        const int m0 = (bx >> 3) * 64;
        const int n0 = (bx & 7) * 64;
        const int srow = tid >> 2;
        const int scol = (tid & 3) * 8;
        const int quad = lane >> 4, r16 = lane & 15;
        f32x4 acc[4];
        #pragma unroll
        for (int mt = 0; mt < 4; ++mt) acc[mt] = (f32x4){0.f, 0.f, 0.f, 0.f};
        const unsigned short* ap = locb + (size_t)(m0 + srow) * 512 + scol;
        const unsigned short* bp = OWt  + (size_t)(n0 + srow) * 512 + scol;
        for (int k0 = 0; k0 < 512; k0 += 32) {
            int4 av = *(const int4*)(ap + k0);
            int4 bv = *(const int4*)(bp + k0);
            __syncthreads();
            *(int4*)&As[srow * 32 + scol] = av;
            *(int4*)&Bs[srow * 32 + scol] = bv;
            __syncthreads();
            bf16x8 bfr = *(const bf16x8*)&Bs[(w * 16 + r16) * 32 + quad * 8];
            #pragma unroll
            for (int mt = 0; mt < 4; ++mt) {
                bf16x8 af = *(const bf16x8*)&As[(mt * 16 + r16) * 32 + quad * 8];
                acc[mt] = __builtin_amdgcn_mfma_f32_16x16x32_bf16(af, bfr, acc[mt], 0, 0, 0);
            }
        }
        const int n = n0 + w * 16 + r16;
        const float bn = outb[n];
        #pragma unroll
        for (int mt = 0; mt < 4; ++mt) {
            #pragma unroll
            for (int i = 0; i < 4; ++i) {
                const int m = m0 + mt * 16 + quad * 4 + i;
                out[(size_t)m * 512 + n] = acc[mt][i] + bn + x[(size_t)m * 512 + n];
            }
        }
    }
}

template<int CCH, int CLEN>
static void run_fused(const float* x, const float* keyw, const float* qryw,
                      const float* vw, const float* vb, const float* lng,
                      const float* lnb, const float* outw, const float* outb,
                      const float* setw, const float* pf, const float* posw,
                      const float* g1w, const float* g1b, const float* g2w,
                      const float* g2b, const float* sscale, const float* sbias,
                      const float* rscale, const float* rthr,
                      float* ws, float* out, hipStream_t stream)
{
    unsigned* bar = (unsigned*)ws;                 // 32 floats reserved
    float* R    = ws + 32;
    float* scal = R + (size_t)NROW * RS;
    float* loc  = scal + (size_t)NROW * 128;
    float* T    = loc + (size_t)NROW * D_;
    unsigned short* W    = (unsigned short*)(T + (size_t)B_ * CCH * 72 * D_);
    unsigned short* locb = W + (size_t)1408 * 512;

    hipMemsetAsync(bar, 0, 128, stream);
    hipLaunchKernelGGL((k_fused<CCH, CLEN>), dim3(NBLK), dim3(256), 0, stream,
        bar, x, keyw, qryw, g1w, vw, outw, g1b, vb, pf, g2w, g2b,
        rscale, rthr, sscale, sbias, setw, posw, lng, lnb, outb,
        R, scal, loc, T, W, locb, out);
}

extern "C" void kernel_launch(void* const* d_in, const int* in_sizes, int n_in,
                              void* d_out, int out_size, void* d_ws, size_t ws_size,
                              hipStream_t stream)
{
    const float* x      = (const float*)d_in[0];
    const float* keyw   = (const float*)d_in[1];
    const float* qryw   = (const float*)d_in[2];
    const float* vw     = (const float*)d_in[4];
    const float* vb     = (const float*)d_in[5];
    const float* lng    = (const float*)d_in[6];
    const float* lnb    = (const float*)d_in[7];
    const float* outw   = (const float*)d_in[8];
    const float* outb   = (const float*)d_in[9];
    const float* setw   = (const float*)d_in[10];
    const float* pf     = (const float*)d_in[11];
    const float* posw   = (const float*)d_in[12];
    const float* g1w    = (const float*)d_in[13];
    const float* g1b    = (const float*)d_in[14];
    const float* g2w    = (const float*)d_in[15];
    const float* g2b    = (const float*)d_in[16];
    const float* sscale = (const float*)d_in[19];
    const float* sbias  = (const float*)d_in[20];
    const float* rscale = (const float*)d_in[21];
    const float* rthr   = (const float*)d_in[22];

    float* ws  = (float*)d_ws;
    float* out = (float*)d_out;

    const size_t base_bytes = 128 + (size_t)(NROW * RS + NROW * 128 + NROW * D_) * 4
                            + ((size_t)1408 * 512 + (size_t)NROW * 512) * 2;
    const size_t per_cch = (size_t)B_ * 72 * D_ * 4;

    if (ws_size >= base_bytes + 64 * per_cch)
        run_fused<64, 16>(x, keyw, qryw, vw, vb, lng, lnb, outw, outb, setw, pf,
                          posw, g1w, g1b, g2w, g2b, sscale, sbias, rscale, rthr,
                          ws, out, stream);
    else
        run_fused<32, 32>(x, keyw, qryw, vw, vb, lng, lnb, outw, outb, setw, pf,
                          posw, g1w, g1b, g2w, g2b, sscale, sbias, rscale, rthr,
                          ws, out, stream);
}

// Round 3
// 185.447 us; speedup vs baseline: 1.7846x; 1.7846x over previous
//
#include <hip/hip_runtime.h>
#include <math.h>

#define B_ 2
#define L_ 1024
#define D_ 512
#define NROW (B_*L_)            // 2048
#define RS 896                  // R stride: key16|query16|g1 256|v 512|pad 96
#define PI_F 3.14159274f
#define TWO_PI_F 6.28318548f

typedef __attribute__((ext_vector_type(8))) short bf16x8;
typedef __attribute__((ext_vector_type(4))) float f32x4;

__device__ __forceinline__ unsigned short f2bf(float f) {
    unsigned u = __float_as_uint(f);
    unsigned r = (u + 0x7FFFu + ((u >> 16) & 1u)) >> 16;
    return (unsigned short)r;
}
__device__ __forceinline__ float bf2f(unsigned short h) {
    return __uint_as_float((unsigned)h << 16);
}

// ---------------- weight prep: tiled transpose + bf16 cast (verified) ----------------
__global__ __launch_bounds__(256) void k_prep_w(
    const float* __restrict__ keyw, const float* __restrict__ qryw,
    const float* __restrict__ g1w, const float* __restrict__ vw,
    const float* __restrict__ outw, unsigned short* __restrict__ W)
{
    const int nt = blockIdx.x % 22;
    const int kt = blockIdx.x / 22;     // 0..7
    const int n0 = nt * 64, k0 = kt * 64;
    __shared__ unsigned short tile[64 * 68];   // [k][n], stride 68
    const int tn = threadIdx.x & 63;
    const int tk4 = threadIdx.x >> 6;   // 0..3
    const int n = n0 + tn;
    const float* src = nullptr; int stride = 0, col = 0;
    if (n < 16)        { src = keyw; stride = 16;  col = n; }
    else if (n < 32)   { src = qryw; stride = 16;  col = n - 16; }
    else if (n < 288)  { src = g1w;  stride = 256; col = n - 32; }
    else if (n < 800)  { src = vw;   stride = 512; col = n - 288; }
    else if (n < 896)  { src = nullptr; }
    else               { src = outw; stride = 512; col = n - 896; }
    #pragma unroll
    for (int r = 0; r < 16; ++r) {
        int k = k0 + tk4 * 16 + r;
        float v = src ? src[(size_t)k * stride + col] : 0.f;
        tile[(tk4 * 16 + r) * 68 + tn] = f2bf(v);
    }
    __syncthreads();
    #pragma unroll
    for (int r = 0; r < 16; ++r) {
        int nn = n0 + tk4 * 16 + r;
        W[(size_t)nn * 512 + k0 + tn] = tile[tn * 68 + tk4 * 16 + r];
    }
}

// ---------------- GEMM1 (MFMA): R[2048][896] = x @ W[0:896]^T (verified) ----------------
__global__ __launch_bounds__(256) void k_gemm1(
    const float* __restrict__ x,
    const unsigned short* __restrict__ Bt,
    const float* __restrict__ g1b, const float* __restrict__ vb,
    float* __restrict__ C)
{
    __shared__ unsigned short As[64 * 32];
    __shared__ unsigned short Bs[128 * 32];
    const int tid = threadIdx.x;
    const int w = tid >> 6;
    const int lane = tid & 63;
    const int m0 = blockIdx.y * 64;
    const int n0 = blockIdx.x * 128;
    const int srow = tid >> 2;
    const int scol = (tid & 3) * 8;

    f32x4 acc[4][2];
    #pragma unroll
    for (int mt = 0; mt < 4; ++mt)
        #pragma unroll
        for (int nt = 0; nt < 2; ++nt)
            acc[mt][nt] = (f32x4){0.f, 0.f, 0.f, 0.f};

    const float* ap = x + (size_t)(m0 + srow) * 512 + scol;
    const unsigned short* bp0 = Bt + (size_t)(n0 + srow) * 512 + scol;
    const unsigned short* bp1 = Bt + (size_t)(n0 + 64 + srow) * 512 + scol;
    const int quad = lane >> 4, r16 = lane & 15;

    for (int k0 = 0; k0 < 512; k0 += 32) {
        float4 a0 = *(const float4*)(ap + k0);
        float4 a1 = *(const float4*)(ap + k0 + 4);
        int4 bv0 = *(const int4*)(bp0 + k0);
        int4 bv1 = *(const int4*)(bp1 + k0);
        int4 av;
        av.x = (int)f2bf(a0.x) | ((int)f2bf(a0.y) << 16);
        av.y = (int)f2bf(a0.z) | ((int)f2bf(a0.w) << 16);
        av.z = (int)f2bf(a1.x) | ((int)f2bf(a1.y) << 16);
        av.w = (int)f2bf(a1.z) | ((int)f2bf(a1.w) << 16);
        __syncthreads();
        *(int4*)&As[srow * 32 + scol] = av;
        *(int4*)&Bs[srow * 32 + scol] = bv0;
        *(int4*)&Bs[(64 + srow) * 32 + scol] = bv1;
        __syncthreads();
        bf16x8 af[4], bfr[2];
        #pragma unroll
        for (int mt = 0; mt < 4; ++mt)
            af[mt] = *(const bf16x8*)&As[(mt * 16 + r16) * 32 + quad * 8];
        #pragma unroll
        for (int nt = 0; nt < 2; ++nt)
            bfr[nt] = *(const bf16x8*)&Bs[(w * 32 + nt * 16 + r16) * 32 + quad * 8];
        #pragma unroll
        for (int mt = 0; mt < 4; ++mt)
            #pragma unroll
            for (int nt = 0; nt < 2; ++nt)
                acc[mt][nt] = __builtin_amdgcn_mfma_f32_16x16x32_bf16(
                    af[mt], bfr[nt], acc[mt][nt], 0, 0, 0);
    }

    #pragma unroll
    for (int mt = 0; mt < 4; ++mt) {
        #pragma unroll
        for (int nt = 0; nt < 2; ++nt) {
            const int n = n0 + w * 32 + nt * 16 + r16;
            float bias = 0.f;
            if (n >= 288 && n < 800) bias = vb[n - 288];
            else if (n >= 32 && n < 288) bias = g1b[n - 32];
            #pragma unroll
            for (int i = 0; i < 4; ++i) {
                const int m = m0 + mt * 16 + quad * 4 + i;
                C[(size_t)m * RS + n] = acc[mt][nt][i] + bias;
            }
        }
    }
}

// ---------------- V transpose + hi/lo bf16 split: Vt[512][2048] ----------------
__global__ __launch_bounds__(256) void k_prep_v(
    const float* __restrict__ R,
    unsigned short* __restrict__ Vthi, unsigned short* __restrict__ Vtlo)
{
    const int mt = blockIdx.x & 31;     // 2048/64
    const int nt = blockIdx.x >> 5;     // 512/64
    const int m0 = mt * 64, n0 = nt * 64;
    __shared__ unsigned short thi[64 * 68];
    __shared__ unsigned short tlo[64 * 68];
    const int tn = threadIdx.x & 63;
    const int tk4 = threadIdx.x >> 6;
    #pragma unroll
    for (int r = 0; r < 16; ++r) {
        int m = m0 + tk4 * 16 + r;
        float v = R[(size_t)m * RS + 288 + n0 + tn];
        unsigned short hi = f2bf(v);
        unsigned short lo = f2bf(v - bf2f(hi));
        thi[(tk4 * 16 + r) * 68 + tn] = hi;
        tlo[(tk4 * 16 + r) * 68 + tn] = lo;
    }
    __syncthreads();
    #pragma unroll
    for (int r = 0; r < 16; ++r) {
        int d = n0 + tk4 * 16 + r;
        Vthi[(size_t)d * 2048 + m0 + tn] = thi[tn * 68 + tk4 * 16 + r];
        Vtlo[(size_t)d * 2048 + m0 + tn] = tlo[tn * 68 + tk4 * 16 + r];
    }
}

// ---------------- phasors, jk/jq, gate (verified minus pos block) ----------------
__global__ __launch_bounds__(256) void k_phasor(
    const float* __restrict__ R,
    const float* __restrict__ g2w, const float* __restrict__ g2b,
    float* __restrict__ scal)
{
    const int row = blockIdx.x * 4 + (threadIdx.x >> 6);
    const int lane = threadIdx.x & 63;
    float* sc = scal + (size_t)row * 128;
    const float* r = R + (size_t)row * RS;

    float part = 0.f;
    #pragma unroll
    for (int j = 0; j < 4; ++j) {
        float v = r[32 + lane * 4 + j];
        float h = 0.5f * v * (1.0f + erff(v * 0.70710678f));
        part += h * g2w[lane * 4 + j];
    }
    #pragma unroll
    for (int off = 32; off > 0; off >>= 1) part += __shfl_down(part, off, 64);
    if (lane == 0) sc[112] = 1.0f / (1.0f + expf(-(part + g2b[0])));

    float pr = 1.f, pim = 0.f;
    if (lane < 32) {
        float a = tanhf(r[lane]) * PI_F;
        float sv, cv;
        sincosf(a, &sv, &cv);
        int t = lane & 15;
        if (lane < 16) { sc[t] = cv; sc[16 + t] = sv; }
        else           { sc[32 + t] = cv; sc[48 + t] = sv; }
        pr = cv; pim = sv;
    }
    #pragma unroll
    for (int m = 4; m <= 8; m <<= 1) {
        float orr = __shfl_xor(pr, m, 64);
        float oii = __shfl_xor(pim, m, 64);
        float nr = pr * orr - pim * oii;
        float ni = pr * oii + pim * orr;
        pr = nr; pim = ni;
    }
    if (lane < 4)                     { sc[64 + lane] = pr; sc[68 + lane] = pim; }
    else if (lane >= 16 && lane < 20) { sc[72 + lane - 16] = pr; sc[76 + lane - 16] = pim; }
}

// ---------------- wg scan (verified, 1024 thr) + Toeplitz table block ----------------
__global__ __launch_bounds__(1024) void k_wg(
    float* __restrict__ scal, const float* __restrict__ pf,
    const float* __restrict__ res_scale, const float* __restrict__ res_thr,
    const float* __restrict__ sur_scale, const float* __restrict__ sur_bias,
    float* __restrict__ gtab)
{
    const int b = blockIdx.x;
    const int l = threadIdx.x;
    if (b == B_) {
        // g(dl) = sum_p cos(2*pi*dl*pf[p])
        float g = 0.f;
        #pragma unroll
        for (int p = 0; p < 16; ++p)
            g += cosf(TWO_PI_F * (float)l * pf[p]);
        gtab[l] = g;
        return;
    }
    const size_t row = (size_t)(b * L_ + l) * 128;
    float v[8], own[8];
    #pragma unroll
    for (int c2 = 0; c2 < 8; ++c2) { v[c2] = scal[row + 64 + c2]; own[c2] = v[c2]; }
    const int lane = l & 63;
    const int wave = l >> 6;
    #pragma unroll
    for (int off = 1; off < 64; off <<= 1) {
        float o[8];
        #pragma unroll
        for (int c2 = 0; c2 < 8; ++c2) o[c2] = __shfl_up(v[c2], off, 64);
        if (lane >= off) {
            #pragma unroll
            for (int c2 = 0; c2 < 8; ++c2) v[c2] += o[c2];
        }
    }
    __shared__ float wtot[16][8];
    if (lane == 63) {
        #pragma unroll
        for (int c2 = 0; c2 < 8; ++c2) wtot[wave][c2] = v[c2];
    }
    __syncthreads();
    float pre[8] = {0,0,0,0,0,0,0,0};
    for (int w2 = 0; w2 < wave; ++w2) {
        #pragma unroll
        for (int c2 = 0; c2 < 8; ++c2) pre[c2] += wtot[w2][c2];
    }
    float km[8];
    #pragma unroll
    for (int c2 = 0; c2 < 8; ++c2) km[c2] = pre[c2] + v[c2] - own[c2];
    float mag = 0.f;
    #pragma unroll
    for (int pp = 0; pp < 4; ++pp) {
        float jqr = scal[row + 72 + pp], jqi = scal[row + 76 + pp];
        float re = km[pp] * jqr + km[4 + pp] * jqi;
        float im = km[4 + pp] * jqr - km[pp] * jqi;
        mag += sqrtf(re * re + im * im);
    }
    mag *= 0.25f;
    float posn = fmaxf((float)l, 1.0f);
    float nres = mag / sqrtf(posn);
    float scl = fminf(fmaxf(res_scale[0], 1.0f), 20.0f);
    float thr = fminf(fmaxf(res_thr[0], 0.1f), 0.9f);
    float sur = 0.5f * (1.0f - tanhf(scl * (nres - thr)));
    float wgv = 1.0f / (1.0f + expf(-(sur_scale[0] * (sur - 0.5f) + sur_bias[0])));
    scal[row + 113] = wgv;
}

// ---------------- build Qf/Kf [2048][64] bf16 (rank-40 factors, padded) ----------------
__global__ __launch_bounds__(256) void k_build(
    const float* __restrict__ scal, const float* __restrict__ setw,
    unsigned short* __restrict__ Qf, unsigned short* __restrict__ Kf)
{
    const int row = blockIdx.x * 8 + (threadIdx.x >> 5);
    const int sub = threadIdx.x & 31;
    const float* sc = scal + (size_t)row * 128;
    const float gate = sc[112], wg = sc[113];

    float s0 = setw[0], s1 = setw[1], s2 = setw[2], s3 = setw[3];
    float mx = fmaxf(fmaxf(s0, s1), fmaxf(s2, s3));
    float e0 = expf(s0 - mx), e1 = expf(s1 - mx), e2 = expf(s2 - mx), e3 = expf(s3 - mx);
    float esum = e0 + e1 + e2 + e3;
    float w4[4] = {e0 / esum, e1 / esum, e2 / esum, e3 / esum};
    const float qs = 0.2f * gate;

    float q0, q1, k0v, k1v;
    if (sub < 16) {
        float wgrp = w4[sub >> 2];
        q0 = qs * wgrp * sc[32 + sub];
        q1 = qs * wgrp * sc[48 + sub];
        k0v = wg * sc[sub];
        k1v = wg * sc[16 + sub];
    } else if (sub < 20) {
        int p = sub - 16;
        q0 = qs * sc[72 + p];
        q1 = qs * sc[76 + p];
        k0v = wg * sc[64 + p];
        k1v = wg * sc[68 + p];
    } else { q0 = q1 = k0v = k1v = 0.f; }

    unsigned qpack = (unsigned)f2bf(q0) | ((unsigned)f2bf(q1) << 16);
    unsigned kpack = (unsigned)f2bf(k0v) | ((unsigned)f2bf(k1v) << 16);
    *(unsigned*)&Qf[(size_t)row * 64 + sub * 2] = qpack;
    *(unsigned*)&Kf[(size_t)row * 64 + sub * 2] = kpack;
}

// ---------------- build A (tril 64x64 tiles): A = Qf@Kf^T + toeplitz, bf16 hi/lo ----------------
__global__ __launch_bounds__(256) void k_buildA(
    const unsigned short* __restrict__ Qf, const unsigned short* __restrict__ Kf,
    const float* __restrict__ scal, const float* __restrict__ gtab,
    const float* __restrict__ posw,
    unsigned short* __restrict__ Ahi, unsigned short* __restrict__ Alo)
{
    const int bx = blockIdx.x;
    const int b = bx / 136;
    const int r = bx % 136;
    int ti = 0;
    while ((ti + 1) * (ti + 2) / 2 <= r) ++ti;
    const int tj = r - ti * (ti + 1) / 2;

    __shared__ unsigned short Qs[64 * 72];
    __shared__ unsigned short Ks[64 * 72];
    const int tid = threadIdx.x;
    const int srow = tid >> 2;
    const int sc16 = (tid & 3) * 16;
    {
        const unsigned short* qsrc = Qf + ((size_t)(b * L_ + ti * 64 + srow)) * 64 + sc16;
        const unsigned short* ksrc = Kf + ((size_t)(b * L_ + tj * 64 + srow)) * 64 + sc16;
        *(int4*)&Qs[srow * 72 + sc16]     = *(const int4*)(qsrc);
        *(int4*)&Qs[srow * 72 + sc16 + 8] = *(const int4*)(qsrc + 8);
        *(int4*)&Ks[srow * 72 + sc16]     = *(const int4*)(ksrc);
        *(int4*)&Ks[srow * 72 + sc16 + 8] = *(const int4*)(ksrc + 8);
    }
    __syncthreads();

    const int w = tid >> 6;
    const int lane = tid & 63;
    const int quad = lane >> 4, r16 = lane & 15;
    f32x4 acc[4];
    #pragma unroll
    for (int mt = 0; mt < 4; ++mt) acc[mt] = (f32x4){0.f, 0.f, 0.f, 0.f};
    #pragma unroll
    for (int kk = 0; kk < 2; ++kk) {
        bf16x8 bfr = *(const bf16x8*)&Ks[(w * 16 + r16) * 72 + kk * 32 + quad * 8];
        #pragma unroll
        for (int mt = 0; mt < 4; ++mt) {
            bf16x8 af = *(const bf16x8*)&Qs[(mt * 16 + r16) * 72 + kk * 32 + quad * 8];
            acc[mt] = __builtin_amdgcn_mfma_f32_16x16x32_bf16(af, bfr, acc[mt], 0, 0, 0);
        }
    }
    const float sw = 1.0f / (1.0f + expf(-posw[0]));
    const int lp = tj * 64 + w * 16 + r16;
    #pragma unroll
    for (int mt = 0; mt < 4; ++mt) {
        #pragma unroll
        for (int i = 0; i < 4; ++i) {
            const int l = ti * 64 + mt * 16 + quad * 4 + i;
            const int dl = l - lp;
            float v = 0.f;
            if (dl >= 0) {
                float gate = scal[((size_t)(b * L_ + l)) * 128 + 112];
                v = acc[mt][i] + (1.0f - gate) * sw * gtab[dl];
            }
            unsigned short hi = f2bf(v);
            unsigned short lo = f2bf(v - bf2f(hi));
            const size_t off = ((size_t)(b * L_ + l)) * 1024 + lp;
            Ahi[off] = hi;
            Alo[off] = lo;
        }
    }
}

// ---------------- AV GEMM (masked, hi/lo split, 3 products): loc = A @ V ----------------
__global__ __launch_bounds__(256) void k_av(
    const unsigned short* __restrict__ Ahi, const unsigned short* __restrict__ Alo,
    const unsigned short* __restrict__ Vthi, const unsigned short* __restrict__ Vtlo,
    float* __restrict__ loc)
{
    const int bx = blockIdx.x;
    const int b = bx >> 7;
    const int ti = (bx >> 3) & 15;      // l tile
    const int nj = bx & 7;              // d tile
    const int m0 = ti * 64, n0 = nj * 64;
    const int kmax = (ti + 1) * 64;

    __shared__ unsigned short Ash[64 * 32];
    __shared__ unsigned short Asl[64 * 32];
    __shared__ unsigned short Bsh[64 * 32];
    __shared__ unsigned short Bsl[64 * 32];
    const int tid = threadIdx.x;
    const int w = tid >> 6;
    const int lane = tid & 63;
    const int srow = tid >> 2;
    const int scol = (tid & 3) * 8;
    const int quad = lane >> 4, r16 = lane & 15;

    f32x4 acc[4];
    #pragma unroll
    for (int mt = 0; mt < 4; ++mt) acc[mt] = (f32x4){0.f, 0.f, 0.f, 0.f};

    const unsigned short* aph = Ahi + ((size_t)(b * L_ + m0 + srow)) * 1024 + scol;
    const unsigned short* apl = Alo + ((size_t)(b * L_ + m0 + srow)) * 1024 + scol;
    const unsigned short* bph = Vthi + (size_t)(n0 + srow) * 2048 + b * L_ + scol;
    const unsigned short* bpl = Vtlo + (size_t)(n0 + srow) * 2048 + b * L_ + scol;

    for (int k0 = 0; k0 < kmax; k0 += 32) {
        int4 ah = *(const int4*)(aph + k0);
        int4 al = *(const int4*)(apl + k0);
        int4 bh = *(const int4*)(bph + k0);
        int4 bl = *(const int4*)(bpl + k0);
        __syncthreads();
        *(int4*)&Ash[srow * 32 + scol] = ah;
        *(int4*)&Asl[srow * 32 + scol] = al;
        *(int4*)&Bsh[srow * 32 + scol] = bh;
        *(int4*)&Bsl[srow * 32 + scol] = bl;
        __syncthreads();
        bf16x8 bh8 = *(const bf16x8*)&Bsh[(w * 16 + r16) * 32 + quad * 8];
        bf16x8 bl8 = *(const bf16x8*)&Bsl[(w * 16 + r16) * 32 + quad * 8];
        #pragma unroll
        for (int mt = 0; mt < 4; ++mt) {
            bf16x8 ah8 = *(const bf16x8*)&Ash[(mt * 16 + r16) * 32 + quad * 8];
            bf16x8 al8 = *(const bf16x8*)&Asl[(mt * 16 + r16) * 32 + quad * 8];
            acc[mt] = __builtin_amdgcn_mfma_f32_16x16x32_bf16(ah8, bh8, acc[mt], 0, 0, 0);
            acc[mt] = __builtin_amdgcn_mfma_f32_16x16x32_bf16(ah8, bl8, acc[mt], 0, 0, 0);
            acc[mt] = __builtin_amdgcn_mfma_f32_16x16x32_bf16(al8, bh8, acc[mt], 0, 0, 0);
        }
    }
    const int n = n0 + w * 16 + r16;
    #pragma unroll
    for (int mt = 0; mt < 4; ++mt) {
        #pragma unroll
        for (int i = 0; i < 4; ++i) {
            const int m = m0 + mt * 16 + quad * 4 + i;
            loc[((size_t)(b * L_ + m)) * 512 + n] = acc[mt][i];
        }
    }
}

// ---------------- LN: y = loc/norm, LayerNorm, bf16 out ----------------
__global__ __launch_bounds__(512) void k_ln(
    const float* __restrict__ loc,
    const float* __restrict__ lng, const float* __restrict__ lnb,
    unsigned short* __restrict__ locb)
{
    const int row = blockIdx.x;
    const int l = row & (L_ - 1);
    const int d = threadIdx.x;
    __shared__ float red[16];
    float y = loc[(size_t)row * 512 + d] / sqrtf(4.0f * (float)(l + 1));
    float s = y, s2v = y * y;
    #pragma unroll
    for (int off = 32; off > 0; off >>= 1) {
        s   += __shfl_down(s, off, 64);
        s2v += __shfl_down(s2v, off, 64);
    }
    const int lane = d & 63, wv = d >> 6;
    if (lane == 0) { red[wv] = s; red[8 + wv] = s2v; }
    __syncthreads();
    float su = 0.f, sq = 0.f;
    #pragma unroll
    for (int w2 = 0; w2 < 8; ++w2) { su += red[w2]; sq += red[8 + w2]; }
    float mu = su * (1.0f / 512.0f);
    float var = sq * (1.0f / 512.0f) - mu * mu;
    float rstd = rsqrtf(var + 1e-5f);
    float yn = (y - mu) * rstd * lng[d] + lnb[d];
    locb[(size_t)row * 512 + d] = f2bf(yn);
}

// ---------------- out GEMM (verified): out = x + yn @ out_w + out_b ----------------
__global__ __launch_bounds__(256) void k_gemm_out(
    const unsigned short* __restrict__ A,
    const unsigned short* __restrict__ Bt,
    const float* __restrict__ bias, const float* __restrict__ resid,
    float* __restrict__ out)
{
    __shared__ unsigned short As[64 * 32];
    __shared__ unsigned short Bs[64 * 32];
    const int tid = threadIdx.x;
    const int w = tid >> 6;
    const int lane = tid & 63;
    const int m0 = blockIdx.y * 64;
    const int n0 = blockIdx.x * 64;
    const int srow = tid >> 2;
    const int scol = (tid & 3) * 8;
    const int quad = lane >> 4, r16 = lane & 15;

    f32x4 acc[4];
    #pragma unroll
    for (int mt = 0; mt < 4; ++mt) acc[mt] = (f32x4){0.f, 0.f, 0.f, 0.f};

    const unsigned short* ap = A  + (size_t)(m0 + srow) * 512 + scol;
    const unsigned short* bp = Bt + (size_t)(n0 + srow) * 512 + scol;

    for (int k0 = 0; k0 < 512; k0 += 32) {
        int4 av = *(const int4*)(ap + k0);
        int4 bv = *(const int4*)(bp + k0);
        __syncthreads();
        *(int4*)&As[srow * 32 + scol] = av;
        *(int4*)&Bs[srow * 32 + scol] = bv;
        __syncthreads();
        bf16x8 bfr = *(const bf16x8*)&Bs[(w * 16 + r16) * 32 + quad * 8];
        #pragma unroll
        for (int mt = 0; mt < 4; ++mt) {
            bf16x8 af = *(const bf16x8*)&As[(mt * 16 + r16) * 32 + quad * 8];
            acc[mt] = __builtin_amdgcn_mfma_f32_16x16x32_bf16(af, bfr, acc[mt], 0, 0, 0);
        }
    }
    const int n = n0 + w * 16 + r16;
    const float bn = bias[n];
    #pragma unroll
    for (int mt = 0; mt < 4; ++mt) {
        #pragma unroll
        for (int i = 0; i < 4; ++i) {
            const int m = m0 + mt * 16 + quad * 4 + i;
            out[(size_t)m * 512 + n] = acc[mt][i] + bn + resid[(size_t)m * 512 + n];
        }
    }
}

extern "C" void kernel_launch(void* const* d_in, const int* in_sizes, int n_in,
                              void* d_out, int out_size, void* d_ws, size_t ws_size,
                              hipStream_t stream)
{
    const float* x      = (const float*)d_in[0];
    const float* keyw   = (const float*)d_in[1];
    const float* qryw   = (const float*)d_in[2];
    const float* vw     = (const float*)d_in[4];
    const float* vb     = (const float*)d_in[5];
    const float* lng    = (const float*)d_in[6];
    const float* lnb    = (const float*)d_in[7];
    const float* outw   = (const float*)d_in[8];
    const float* outb   = (const float*)d_in[9];
    const float* setw   = (const float*)d_in[10];
    const float* pf     = (const float*)d_in[11];
    const float* posw   = (const float*)d_in[12];
    const float* g1w    = (const float*)d_in[13];
    const float* g1b    = (const float*)d_in[14];
    const float* g2w    = (const float*)d_in[15];
    const float* g2b    = (const float*)d_in[16];
    const float* sscale = (const float*)d_in[19];
    const float* sbias  = (const float*)d_in[20];
    const float* rscale = (const float*)d_in[21];
    const float* rthr   = (const float*)d_in[22];

    char* wsb = (char*)d_ws;
    // A (8MB) aliases R (7.34MB): R dead before k_buildA writes A.
    unsigned short* Ahi  = (unsigned short*)(wsb + 0);
    unsigned short* Alo  = (unsigned short*)(wsb + 4194304);
    float*          R    = (float*)(wsb + 0);
    float*          scal = (float*)(wsb + 8388608);
    float*          loc  = (float*)(wsb + 9437184);
    unsigned short* W    = (unsigned short*)(wsb + 13631488);
    unsigned short* locb = (unsigned short*)(wsb + 15073280);
    unsigned short* Vthi = (unsigned short*)(wsb + 17170432);
    unsigned short* Vtlo = (unsigned short*)(wsb + 19267584);
    unsigned short* Qf   = (unsigned short*)(wsb + 21364736);
    unsigned short* Kf   = (unsigned short*)(wsb + 21626880);
    float*          gtab = (float*)(wsb + 21889024);

    float* out = (float*)d_out;

    k_prep_w<<<176, 256, 0, stream>>>(keyw, qryw, g1w, vw, outw, W);
    k_gemm1<<<dim3(7, 32), 256, 0, stream>>>(x, W, g1b, vb, R);
    k_prep_v<<<256, 256, 0, stream>>>(R, Vthi, Vtlo);
    k_phasor<<<NROW / 4, 256, 0, stream>>>(R, g2w, g2b, scal);
    k_wg<<<B_ + 1, 1024, 0, stream>>>(scal, pf, rscale, rthr, sscale, sbias, gtab);
    k_build<<<256, 256, 0, stream>>>(scal, setw, Qf, Kf);
    k_buildA<<<2 * 136, 256, 0, stream>>>(Qf, Kf, scal, gtab, posw, Ahi, Alo);
    k_av<<<256, 256, 0, stream>>>(Ahi, Alo, Vthi, Vtlo, loc);
    k_ln<<<NROW, 512, 0, stream>>>(loc, lng, lnb, locb);
    k_gemm_out<<<dim3(8, 32), 256, 0, stream>>>(locb, W + (size_t)896 * 512, outb, x, out);
}